// Round 19
// baseline (83.320 us; speedup 1.0000x reference)
//
#include <hip/hip_runtime.h>
#include <hip/hip_bf16.h>

// u[b,o,y,x] = sum_d dist(p,d) * t[b,d,o],  t = v@W^T + bias
// GEMM: out[col*9216 + p] = sum_d D[p,d] * T2[col][d],  col = b*32+o
// R7's PASSING kernel text (69.7us gemm, absmax 2.0) with one change:
// NSPLIT 12 -> 7 (KCHUNK=1344, variable nt 21/18) so grid = 72x2x7 = 1008
// <= 1024 resident capacity (4 blocks/CU) -> single pass, zero tail.
// Structure: 256 thr = 4 waves stacked rows (wave 32r x 128c, acc 1x4 =
// 64 AGPR), tile 128r x 128c, BK=64 dbuf (32KB LDS), perm-pack agen,
// f16 partials + f16x8 reduce.

typedef __bf16    bf16x8 __attribute__((ext_vector_type(8)));
typedef float     f32x4  __attribute__((ext_vector_type(4)));
typedef float     f32x16 __attribute__((ext_vector_type(16)));
typedef _Float16  f16x4  __attribute__((ext_vector_type(4)));
typedef _Float16  f16x8  __attribute__((ext_vector_type(8)));

#define NPTS   9216      // 96*96
#define CIN    32
#define COUT   32
#define NCOLS  256       // 8 batches * 32 cout
#define SCALE  (1.0f / 95.0f)
#define OUTN   (NCOLS * NPTS)
#define NSPLIT 7
#define KCHUNK 1344      // 14*96 (last chunk 1152 = 12*96)

// ---------------- Kernel 1: projection  T2[col][d] = bf16(v . W^T + b) ----
__global__ __launch_bounds__(256) void proj_kernel(
    const float* __restrict__ v, const float* __restrict__ W,
    const float* __restrict__ bias, __bf16* __restrict__ T2)
{
    __shared__ float Wl[COUT * CIN];
    __shared__ float bl[COUT];
    const int t = threadIdx.x;
    for (int i = t; i < COUT * CIN; i += 256) Wl[i] = W[i];
    if (t < COUT) bl[t] = bias[t];
    __syncthreads();

    const int b = blockIdx.y;
    const int d = blockIdx.x * 256 + t;
    const float* vb = v + (size_t)b * CIN * NPTS + d;

    float acc[COUT];
#pragma unroll
    for (int o = 0; o < COUT; ++o) acc[o] = bl[o];
#pragma unroll 4
    for (int c = 0; c < CIN; ++c) {
        const float vv = vb[(size_t)c * NPTS];
#pragma unroll
        for (int o = 0; o < COUT; ++o) acc[o] += vv * Wl[o * CIN + c];
    }
#pragma unroll
    for (int o = 0; o < COUT; ++o)
        T2[(size_t)(b * COUT + o) * NPTS + d] = (__bf16)acc[o];
}

// ---------------- A-fragment generator (R7's perm-pack form) --------------
// dist values packed to bf16 via round-half-up + v_perm.
__device__ __forceinline__ bf16x8 agen(float dx, float dy2) {
    float f[8];
#pragma unroll
    for (int j = 0; j < 8; ++j) {
        f[j] = __builtin_amdgcn_sqrtf(__builtin_fmaf(dx, dx, dy2));
        dx -= SCALE;
    }
    union { unsigned int u[4]; bf16x8 v; } pk;
#pragma unroll
    for (int q = 0; q < 4; ++q) {
        const unsigned int lo = __builtin_bit_cast(unsigned int, f[2*q])   + 0x8000u;
        const unsigned int hi = __builtin_bit_cast(unsigned int, f[2*q+1]) + 0x8000u;
        pk.u[q] = __builtin_amdgcn_perm(hi, lo, 0x07060302u);  // [hi16(hi)|hi16(lo)]
    }
    return pk.v;
}

// ---------------- Kernel 2: implicit-D GEMM (R7 text) --------------------
__global__ __launch_bounds__(256, 4) void gemm_kernel(
    const __bf16* __restrict__ T2, void* __restrict__ dst, int usePartial)
{
    __shared__ __align__(1024) unsigned char lds[2][16384];

    const int tid  = threadIdx.x;
    const int wid  = tid >> 6;
    const int lane = tid & 63;
    const int l31  = lane & 31;
    const int hi   = lane >> 5;      // k-half within frag

    const int bid = blockIdx.x;
    const int z   = bid % NSPLIT;    // k-chunk id
    const int rem = bid / NSPLIT;
    const int cb  = rem & 1;         // col-block 0..1
    const int x   = rem >> 1;        // row-block 0..71
    const int koff = z * KCHUNK;
    const int nt   = (z == NSPLIT - 1) ? 18 : 21;   // BK=64 tiles
    const int colBase = cb * 128;

    const int prow = x * 128 + wid * 32 + l31;   // this lane's A row
    const int yp = prow / 96, xp = prow - yp * 96;
    const int xph = xp - hi * 8;     // hi fold pre-applied

    // hoisted LDS B-read byte offsets boff[s][n] (lane-constant)
    int boff[4][4];
#pragma unroll
    for (int s = 0; s < 4; ++s)
#pragma unroll
        for (int n = 0; n < 4; ++n) {
            const int col  = n * 32 + l31;
            const int slot = (s * 2 + hi) ^ (col & 7);
            boff[s][n] = col * 128 + slot * 16;
        }

    // staging: 4 x gload16 per buffer; dest = buf + i*4096 + tid*16
    // (wave-uniform base + lane*16). LDS layout: [col][8 chunks of 16B],
    // physical chunk = logical ^ (col&7); source pre-swizzled to match.
    const int scol = tid >> 3;               // col 0..31 (+32*i)
    const int sch  = (tid & 7) ^ (scol & 7);
    const __bf16* gsrc = T2 + (size_t)(colBase + scol) * NPTS + koff + sch * 8;
    const int ldst = tid * 16;

    auto stage = [&](unsigned char* buf, int kt) {
#pragma unroll
        for (int i = 0; i < 4; ++i)
            __builtin_amdgcn_global_load_lds(
                (const __attribute__((address_space(1))) void*)
                    (gsrc + (size_t)kt * 64 + (size_t)i * 32 * NPTS),
                (__attribute__((address_space(3))) void*)
                    (buf + i * 4096 + ldst),
                16, 0, 0);
    };

    f32x16 acc[4];
#pragma unroll
    for (int n = 0; n < 4; ++n) acc[n] = (f32x16)(0.0f);

    stage(lds[0], 0);
    __syncthreads();

    int xt = 0, yt = z * 14;         // k-tile base coords (koff%96 == 0)
    int cur = 0;
    for (int kt = 0; kt < nt; ++kt) {
        if (kt + 1 < nt) stage(lds[cur ^ 1], kt + 1);
        const unsigned char* Lb = lds[cur];

#pragma unroll
        for (int s = 0; s < 4; ++s) {        // 4 k-steps of 16
            const int xr = xt + s * 16;
            const int xk = (xr >= 96) ? xr - 96 : xr;
            const int yk = (xr >= 96) ? yt + 1  : yt;
            const float dy = (float)(yp - yk) * SCALE;
            const bf16x8 a = agen((float)(xph - xk) * SCALE, dy * dy);
#pragma unroll
            for (int n = 0; n < 4; ++n) {
                const bf16x8 b = *(const bf16x8*)(Lb + boff[s][n]);
                acc[n] = __builtin_amdgcn_mfma_f32_32x32x16_bf16(
                    a, b, acc[n], 0, 0, 0);
            }
        }
        xt += 64; if (xt >= 96) { xt -= 96; ++yt; }
        __syncthreads();
        cur ^= 1;
    }

    // epilogue: 32x32 C/D: col=lane&31, row=(r&3)+8*(r>>2)+4*hi
    const int rowb = x * 128 + wid * 32;
    if (usePartial) {
        _Float16* pb = (_Float16*)dst + (size_t)z * OUTN;
#pragma unroll
        for (int n = 0; n < 4; ++n) {
            const int col = colBase + n * 32 + l31;
            _Float16* ob = pb + (size_t)col * NPTS + rowb + 4 * hi;
#pragma unroll
            for (int q = 0; q < 4; ++q) {
                f16x4 h = { (_Float16)acc[n][4*q],
                            (_Float16)acc[n][4*q+1],
                            (_Float16)acc[n][4*q+2],
                            (_Float16)acc[n][4*q+3] };
                *(f16x4*)(ob + q * 8) = h;
            }
        }
    } else {
        float* ob0 = (float*)dst;
#pragma unroll
        for (int n = 0; n < 4; ++n) {
            const int col = colBase + n * 32 + l31;
            float* ob = ob0 + (size_t)col * NPTS + rowb + 4 * hi;
#pragma unroll
            for (int q = 0; q < 4; ++q)
#pragma unroll
                for (int r = 0; r < 4; ++r)
                    atomicAdd(ob + q * 8 + r, acc[n][4*q+r]);
        }
    }
}

// ---------------- Kernel 3: reduce NSPLIT f16 partials --------------------
__global__ __launch_bounds__(256) void reduce_kernel(
    const _Float16* __restrict__ part, float* __restrict__ out)
{
    const size_t i = ((size_t)blockIdx.x * 256 + threadIdx.x) * 8;
    float a[8] = {};
#pragma unroll
    for (int s = 0; s < NSPLIT; ++s) {
        f16x8 v = *(const f16x8*)(part + (size_t)s * OUTN + i);
#pragma unroll
        for (int r = 0; r < 8; ++r) a[r] += (float)v[r];
    }
    f32x4 o0 = { a[0], a[1], a[2], a[3] };
    f32x4 o1 = { a[4], a[5], a[6], a[7] };
    *(f32x4*)(out + i)     = o0;
    *(f32x4*)(out + i + 4) = o1;
}

extern "C" void kernel_launch(void* const* d_in, const int* in_sizes, int n_in,
                              void* d_out, int out_size, void* d_ws, size_t ws_size,
                              hipStream_t stream) {
    const float* v    = (const float*)d_in[0];  // (8,32,96,96)
    const float* W    = (const float*)d_in[1];  // (32,32)
    const float* bias = (const float*)d_in[2];  // (32,)
    float* out = (float*)d_out;                 // (8,32,96,96) f32

    __bf16* T2 = (__bf16*)d_ws;                 // 256 x 9216 bf16 = 4.72 MB
    const size_t t2b = (size_t)NCOLS * NPTS * 2;
    _Float16* partial = (_Float16*)((char*)d_ws + t2b);
    const size_t need = t2b + (size_t)NSPLIT * OUTN * 2;  // + 33 MB
    const int usePartial = (ws_size >= need) ? 1 : 0;

    proj_kernel<<<dim3(36, 8), 256, 0, stream>>>(v, W, bias, T2);
    if (usePartial) {
        gemm_kernel<<<72 * 2 * NSPLIT, 256, 0, stream>>>(T2, partial, 1);
        reduce_kernel<<<OUTN / 2048, 256, 0, stream>>>(partial, out);
    } else {
        hipMemsetAsync(d_out, 0, (size_t)out_size * sizeof(float), stream);
        gemm_kernel<<<72 * 2 * NSPLIT, 256, 0, stream>>>(T2, out, 0);
    }
}

// Round 20
// 78.669 us; speedup vs baseline: 1.0591x; 1.0591x over previous
//
#include <hip/hip_runtime.h>
#include <hip/hip_bf16.h>

// u[b,o,y,x] = sum_d dist(p,d) * t[b,d,o],  t = v@W^T + bias
// GEMM: out[col*9216 + p] = sum_d D[p,d] * T2[col][d],  col = b*32+o
// dup=1 structure (R17) with the PERM-PACK agen (R6/R7/R8/R19-proven;
// the inline-asm cvt_pk agen is implicated in all 5 structure failures).
// 4 waves each own 32 rows x ALL 256 cols (acc 1x8 = 128 AGPR) -> chip
// sqrt work halves vs dup=2. Tile 128r x 256c, BK=64 dbuf (64KB LDS),
// NSPLIT=7, grid 504 single pass, f16 partials + reduce.

typedef __bf16    bf16x8 __attribute__((ext_vector_type(8)));
typedef float     f32x4  __attribute__((ext_vector_type(4)));
typedef float     f32x16 __attribute__((ext_vector_type(16)));
typedef _Float16  f16x4  __attribute__((ext_vector_type(4)));
typedef _Float16  f16x8  __attribute__((ext_vector_type(8)));

#define NPTS   9216      // 96*96
#define CIN    32
#define COUT   32
#define NCOLS  256       // 8 batches * 32 cout
#define SCALE  (1.0f / 95.0f)
#define OUTN   (NCOLS * NPTS)
#define NSPLIT 7
#define KCHUNK 1344      // 14*96 (last chunk 1152 = 12*96)

// ---------------- Kernel 1: projection  T2[col][d] = bf16(v . W^T + b) ----
__global__ __launch_bounds__(256) void proj_kernel(
    const float* __restrict__ v, const float* __restrict__ W,
    const float* __restrict__ bias, __bf16* __restrict__ T2)
{
    __shared__ float Wl[COUT * CIN];
    __shared__ float bl[COUT];
    const int t = threadIdx.x;
    for (int i = t; i < COUT * CIN; i += 256) Wl[i] = W[i];
    if (t < COUT) bl[t] = bias[t];
    __syncthreads();

    const int b = blockIdx.y;
    const int d = blockIdx.x * 256 + t;
    const float* vb = v + (size_t)b * CIN * NPTS + d;

    float acc[COUT];
#pragma unroll
    for (int o = 0; o < COUT; ++o) acc[o] = bl[o];
#pragma unroll 4
    for (int c = 0; c < CIN; ++c) {
        const float vv = vb[(size_t)c * NPTS];
#pragma unroll
        for (int o = 0; o < COUT; ++o) acc[o] += vv * Wl[o * CIN + c];
    }
#pragma unroll
    for (int o = 0; o < COUT; ++o)
        T2[(size_t)(b * COUT + o) * NPTS + d] = (__bf16)acc[o];
}

// ---------------- A-fragment generator (perm-pack, R6/R7/R8/R19-proven) ---
// dist values packed to bf16 via round-half-up + v_perm. NO inline asm.
__device__ __forceinline__ bf16x8 agen(float dx, float dy2) {
    float f[8];
#pragma unroll
    for (int j = 0; j < 8; ++j) {
        f[j] = __builtin_amdgcn_sqrtf(__builtin_fmaf(dx, dx, dy2));
        dx -= SCALE;
    }
    union { unsigned int u[4]; bf16x8 v; } pk;
#pragma unroll
    for (int q = 0; q < 4; ++q) {
        const unsigned int lo = __builtin_bit_cast(unsigned int, f[2*q])   + 0x8000u;
        const unsigned int hi = __builtin_bit_cast(unsigned int, f[2*q+1]) + 0x8000u;
        pk.u[q] = __builtin_amdgcn_perm(hi, lo, 0x07060302u);  // [hi16(hi)|hi16(lo)]
    }
    return pk.v;
}

// ---------------- Kernel 2: implicit-D GEMM (dup=1) ----------------------
__global__ __launch_bounds__(256, 2) void gemm_kernel(
    const __bf16* __restrict__ T2, void* __restrict__ dst, int usePartial)
{
    __shared__ __align__(1024) unsigned char lds[2][32768];

    const int tid  = threadIdx.x;
    const int wid  = tid >> 6;
    const int lane = tid & 63;
    const int l31  = lane & 31;
    const int hi   = lane >> 5;      // k-half within frag

    const int bid = blockIdx.x;
    const int z   = bid / 72;        // k-chunk id 0..6
    const int x   = bid - z * 72;    // row-block id 0..71
    const int koff = z * KCHUNK;
    const int nt   = (z == NSPLIT - 1) ? 18 : 21;   // BK=64 tiles

    // dup=1 remap: each wave owns 32 rows (wid*32), covers all 256 cols
    const int pbase = x * 128 + wid * 32;
    const int prow  = pbase + l31;   // this lane's A row
    const int yp = prow / 96, xp = prow - yp * 96;
    const int xph = xp - hi * 8;     // hi fold pre-applied

    // hoisted LDS B-read byte offsets boff[s][n] (lane-constant), n=0..7
    int boff[4][8];
#pragma unroll
    for (int s = 0; s < 4; ++s)
#pragma unroll
        for (int n = 0; n < 8; ++n) {
            const int col  = n * 32 + l31;
            const int slot = (s * 2 + hi) ^ (col & 7);
            boff[s][n] = col * 128 + slot * 16;
        }

    // staging: 8 x gload16 per buffer; dest linear tid*16 within 4KB rows;
    // source chunk pre-swizzled so LDS slot = logical ^ (col&7).
    const int scol = tid >> 3;               // col 0..31 (+32*i)
    const int sch  = (tid & 7) ^ (scol & 7);
    const __bf16* gsrc = T2 + (size_t)scol * NPTS + koff + sch * 8;
    const int ldst = tid * 16;

    auto stage = [&](int buf, int kt) {
#pragma unroll
        for (int i = 0; i < 8; ++i)
            __builtin_amdgcn_global_load_lds(
                (const __attribute__((address_space(1))) void*)
                    (gsrc + (size_t)kt * 64 + (size_t)i * 32 * NPTS),
                (__attribute__((address_space(3))) void*)
                    (&lds[buf][i * 4096 + ldst]),
                16, 0, 0);
    };

    f32x16 acc[8];
#pragma unroll
    for (int n = 0; n < 8; ++n) acc[n] = (f32x16)(0.0f);

    stage(0, 0);
    __syncthreads();

    int xt = 0, yt = z * 14;         // k-tile base coords (koff%96==0)
    int cur = 0;
    for (int kt = 0; kt < nt; ++kt) {
        if (kt + 1 < nt) stage(cur ^ 1, kt + 1);
        const unsigned char* Lb = lds[cur];

#pragma unroll
        for (int s = 0; s < 4; ++s) {        // 4 k-steps of 16
            const int xr = xt + s * 16;
            const int xk = (xr >= 96) ? xr - 96 : xr;
            const int yk = (xr >= 96) ? yt + 1  : yt;
            const float dy = (float)(yp - yk) * SCALE;
            const bf16x8 a = agen((float)(xph - xk) * SCALE, dy * dy);
#pragma unroll
            for (int n = 0; n < 8; ++n) {
                const bf16x8 b = *(const bf16x8*)(Lb + boff[s][n]);
                acc[n] = __builtin_amdgcn_mfma_f32_32x32x16_bf16(
                    a, b, acc[n], 0, 0, 0);
            }
        }
        xt += 64; if (xt >= 96) { xt -= 96; ++yt; }
        __syncthreads();
        cur ^= 1;
    }

    // epilogue: 32x32 C/D: col=lane&31, row=(r&3)+8*(r>>2)+4*hi
    if (usePartial) {
        _Float16* pb = (_Float16*)dst + (size_t)z * OUTN;
#pragma unroll
        for (int n = 0; n < 8; ++n) {
            const int col = n * 32 + l31;
            _Float16* ob = pb + (size_t)col * NPTS + pbase + 4 * hi;
#pragma unroll
            for (int q = 0; q < 4; ++q) {
                f16x4 h = { (_Float16)acc[n][4*q],
                            (_Float16)acc[n][4*q+1],
                            (_Float16)acc[n][4*q+2],
                            (_Float16)acc[n][4*q+3] };
                *(f16x4*)(ob + q * 8) = h;
            }
        }
    } else {
        float* ob0 = (float*)dst;
#pragma unroll
        for (int n = 0; n < 8; ++n) {
            const int col = n * 32 + l31;
            float* ob = ob0 + (size_t)col * NPTS + pbase + 4 * hi;
#pragma unroll
            for (int q = 0; q < 4; ++q)
#pragma unroll
                for (int r = 0; r < 4; ++r)
                    atomicAdd(ob + q * 8 + r, acc[n][4*q+r]);
        }
    }
}

// ---------------- Kernel 3: reduce NSPLIT f16 partials --------------------
__global__ __launch_bounds__(256) void reduce_kernel(
    const _Float16* __restrict__ part, float* __restrict__ out)
{
    const size_t i = ((size_t)blockIdx.x * 256 + threadIdx.x) * 8;
    float a[8] = {};
#pragma unroll
    for (int s = 0; s < NSPLIT; ++s) {
        f16x8 v = *(const f16x8*)(part + (size_t)s * OUTN + i);
#pragma unroll
        for (int r = 0; r < 8; ++r) a[r] += (float)v[r];
    }
    f32x4 o0 = { a[0], a[1], a[2], a[3] };
    f32x4 o1 = { a[4], a[5], a[6], a[7] };
    *(f32x4*)(out + i)     = o0;
    *(f32x4*)(out + i + 4) = o1;
}

extern "C" void kernel_launch(void* const* d_in, const int* in_sizes, int n_in,
                              void* d_out, int out_size, void* d_ws, size_t ws_size,
                              hipStream_t stream) {
    const float* v    = (const float*)d_in[0];  // (8,32,96,96)
    const float* W    = (const float*)d_in[1];  // (32,32)
    const float* bias = (const float*)d_in[2];  // (32,)
    float* out = (float*)d_out;                 // (8,32,96,96) f32

    __bf16* T2 = (__bf16*)d_ws;                 // 256 x 9216 bf16 = 4.72 MB
    const size_t t2b = (size_t)NCOLS * NPTS * 2;
    _Float16* partial = (_Float16*)((char*)d_ws + t2b);
    const size_t need = t2b + (size_t)NSPLIT * OUTN * 2;  // + 33 MB
    const int usePartial = (ws_size >= need) ? 1 : 0;

    proj_kernel<<<dim3(36, 8), 256, 0, stream>>>(v, W, bias, T2);
    if (usePartial) {
        gemm_kernel<<<72 * NSPLIT, 256, 0, stream>>>(T2, partial, 1);
        reduce_kernel<<<OUTN / 2048, 256, 0, stream>>>(partial, out);
    } else {
        hipMemsetAsync(d_out, 0, (size_t)out_size * sizeof(float), stream);
        gemm_kernel<<<72 * NSPLIT, 256, 0, stream>>>(T2, out, 0);
    }
}